// Round 23
// baseline (108.127 us; speedup 1.0000x reference)
//
#include <hip/hip_runtime.h>

#define FFT_N 4096
#define NT    256
// additive skew in 8-byte units: +1 per 16 (r19-verified: conflicts ~0.5e6)
#define SK(i) ((i) + ((i) >> 4))
// base-4 digit-reverse involution for 16: P(m) = ((m&3)<<2)|(m>>2)
#define PM(m) ((((m) & 3) << 2) | ((m) >> 2))

typedef float  f2  __attribute__((ext_vector_type(2)));  // lane = row: (row0, row1)
typedef __fp16 h2v __attribute__((ext_vector_type(2)));
typedef __fp16 h4  __attribute__((ext_vector_type(4)));  // LDS: re0, re1, im0, im1

__device__ __forceinline__ f2 mk2(float a, float b) { f2 v; v.x = a; v.y = b; return v; }
__device__ __forceinline__ h4 packh(f2 re, f2 im) {
    h2v r = __builtin_amdgcn_cvt_pkrtz(re.x, re.y);
    h2v i = __builtin_amdgcn_cvt_pkrtz(im.x, im.y);
    h4 v; v.x = r.x; v.y = r.y; v.z = i.x; v.w = i.y;
    return v;
}

// In-place 16-point DFT, SoA over rows (verified r18/r19/r22).
// IMONLY (SGN=+1, PERMIN=false only): final layer computes im outputs only.
template <int SGN, bool PERMIN, bool IMONLY = false>
__device__ __forceinline__ void ip16(f2* re, f2* im) {
    const float C1 = 0.92387953251128675613f;   // cos(pi/8)
    const float S1 = 0.38268343236508977173f;   // sin(pi/8)
    const float R2 = 0.70710678118654752440f;   // sqrt(2)/2
#define BF4(i0, i1, i2, i3) do { \
        f2 t0r = re[i0] + re[i2], t0i = im[i0] + im[i2]; \
        f2 t1r = re[i0] - re[i2], t1i = im[i0] - im[i2]; \
        f2 t2r = re[i1] + re[i3], t2i = im[i1] + im[i3]; \
        f2 t3r = re[i1] - re[i3], t3i = im[i1] - im[i3]; \
        re[i0] = t0r + t2r; im[i0] = t0i + t2i; \
        re[i2] = t0r - t2r; im[i2] = t0i - t2i; \
        if (SGN < 0) { re[i1] = t1r + t3i; im[i1] = t1i - t3r; \
                       re[i3] = t1r - t3i; im[i3] = t1i + t3r; } \
        else         { re[i1] = t1r - t3i; im[i1] = t1i + t3r; \
                       re[i3] = t1r + t3i; im[i3] = t1i - t3r; } \
    } while (0)
    // im-only final butterfly (SGN=+1): im[i0]=t0i+t2i, im[i2]=t0i-t2i,
    // im[i1]=t1i+t3r, im[i3]=t1i-t3r  (signs match the full SGN=+1 path)
#define BF4IM(i0, i1, i2, i3) do { \
        f2 t0i = im[i0] + im[i2], t1i = im[i0] - im[i2]; \
        f2 t2i = im[i1] + im[i3], t3r = re[i1] - re[i3]; \
        im[i0] = t0i + t2i; im[i2] = t0i - t2i; \
        im[i1] = t1i + t3r; im[i3] = t1i - t3r; \
    } while (0)
#define TWM(m, cr, ci) do { \
        f2 rr_ = re[m], ii_ = im[m]; \
        if (SGN < 0) { re[m] = rr_ * (cr) + ii_ * (ci); im[m] = ii_ * (cr) - rr_ * (ci); } \
        else         { re[m] = rr_ * (cr) - ii_ * (ci); im[m] = ii_ * (cr) + rr_ * (ci); } \
    } while (0)
    if (!PERMIN) { BF4(0, 4, 8, 12); BF4(1, 5, 9, 13); BF4(2, 6, 10, 14); BF4(3, 7, 11, 15); }
    else         { BF4(0, 1, 2, 3);  BF4(4, 5, 6, 7);  BF4(8, 9, 10, 11); BF4(12, 13, 14, 15); }
    TWM(5,  C1, S1);    // w1
    TWM(6,  R2, R2);    // w2
    TWM(7,  S1, C1);    // w3
    TWM(9,  R2, R2);    // w2
    {   // x[10] *= S*i
        f2 rr_ = re[10], ii_ = im[10];
        if (SGN < 0) { re[10] = ii_; im[10] = mk2(0.f, 0.f) - rr_; }
        else         { re[10] = mk2(0.f, 0.f) - ii_; im[10] = rr_; }
    }
    TWM(11, -R2, R2);   // w6
    TWM(13, S1, C1);    // w3
    TWM(14, -R2, R2);   // w6
    TWM(15, -C1, -S1);  // w9
    if (!PERMIN) {
        if (IMONLY) { BF4IM(0, 1, 2, 3); BF4IM(4, 5, 6, 7); BF4IM(8, 9, 10, 11); BF4IM(12, 13, 14, 15); }
        else        { BF4(0, 1, 2, 3);   BF4(4, 5, 6, 7);   BF4(8, 9, 10, 11);   BF4(12, 13, 14, 15); }
    } else { BF4(0, 4, 8, 12); BF4(1, 5, 9, 13); BF4(2, 6, 10, 14); BF4(3, 7, 11, 15); }
#undef BF4
#undef BF4IM
#undef TWM
}

typedef float cplx __attribute__((ext_vector_type(2)));
// d_ws: twA[4096] = W4096^(t*r) at [r*256+t]; twB[256] = W256^(j*r) at [r*16+j]
__global__ void twiddle_init(cplx* __restrict__ twA, cplx* __restrict__ twB) {
    int m = blockIdx.x * NT + threadIdx.x;   // 0..4351
    if (m >= 4352) return;
    float s, c;
    if (m < 4096) {
        int r = m >> 8, t = m & 255;
        sincosf(-6.28318530717958647692f * (float)(t * r) / 4096.0f, &s, &c);
        cplx v; v.x = c; v.y = s; twA[m] = v;
    } else {
        int k = m - 4096;                    // k = r*16 + j
        int r = k >> 4, j = k & 15;
        sincosf(-6.28318530717958647692f * (float)(j * r) / 256.0f, &s, &c);
        cplx v; v.x = c; v.y = s; twB[k] = v;
    }
}

__global__ __launch_bounds__(NT) void circconv4096_kernel(
    const float* __restrict__ A, const float* __restrict__ Bv,
    float* __restrict__ O,
    const cplx* __restrict__ twA, const cplx* __restrict__ twB)
{
    // two rows per block, row-packed 4xf16 per element (b64): 34.8 KB -> 4 blocks/CU
    __shared__ h4 Z[SK(4095) + 1];
    const int t = threadIdx.x;
    const size_t r0 = (size_t)blockIdx.x * 2;
    const float* a0 = A + r0 * FFT_N;
    const float* b0 = Bv + r0 * FFT_N;
    const float* a1 = a0 + FFT_N;
    const float* b1 = b0 + FFT_N;
    float* o0 = O + r0 * FFT_N;
    float* o1 = o0 + FFT_N;

    f2 re[16], im[16];

#define TWF(m, w) do { f2 rr_ = re[m], ii_ = im[m]; float wr_ = (w).x, wi_ = (w).y; \
        re[m] = rr_ * wr_ - ii_ * wi_; im[m] = rr_ * wi_ + ii_ * wr_; } while (0)
#define TWC(m, w) do { f2 rr_ = re[m], ii_ = im[m]; float wr_ = (w).x, wi_ = (w).y; \
        re[m] = rr_ * wr_ + ii_ * wi_; im[m] = ii_ * wr_ - rr_ * wi_; } while (0)

    const int j = t & 15;
    const int base = ((t >> 4) << 8) + j;

    // ---- fwd stage 1 (stride 256): coalesced loads, both rows ----
#pragma unroll
    for (int q = 0; q < 16; ++q) {
        int g = t + 256 * q;
        re[q] = mk2(a0[g], a1[g]);
        im[q] = mk2(b0[g], b1[g]);   // z = a + i*b per row
    }
    // prefetch fwd2's twiddles (PM order) before the barrier; dies at fwd2
    cplx wB1[15];
#pragma unroll
    for (int q = 1; q < 16; ++q) wB1[q - 1] = twB[PM(q) * 16 + j];

    ip16<-1, false>(re, im);
#pragma unroll
    for (int m = 1; m < 16; ++m) { cplx w = twA[PM(m) * 256 + t]; TWF(m, w); }
#pragma unroll
    for (int m = 0; m < 16; ++m) Z[SK(t + 256 * PM(m))] = packh(re[m], im[m]);
    __syncthreads();

    // ---- fwd stage 2 (stride 16, wave-private): twiddles in registers ----
#pragma unroll
    for (int q = 0; q < 16; ++q) {
        h4 v = Z[SK(base + 16 * q)];
        re[q] = mk2((float)v.x, (float)v.y); im[q] = mk2((float)v.z, (float)v.w);
    }
    ip16<-1, false>(re, im);
#pragma unroll
    for (int m = 1; m < 16; ++m) TWF(m, wB1[m - 1]);   // wB1[m-1] = twB[PM(m)*16+j]
    __builtin_amdgcn_wave_barrier();
#pragma unroll
    for (int m = 0; m < 16; ++m) Z[SK(base + 16 * PM(m))] = packh(re[m], im[m]);
    __builtin_amdgcn_wave_barrier();

    // ---- fwd stage 3 (contig) + scaled square + inv stage 1 (contig) ----
    // prefetch inv2's twiddles (natural order) now; latency hides under this block
    cplx wB2[15];
#pragma unroll
    for (int q = 1; q < 16; ++q) wB2[q - 1] = twB[q * 16 + j];
    {
        const int b3 = t * 16;
        const float s = 1.0f / 8192.0f;   // fold /4096 (ifft) and /2 (imag trick)
#pragma unroll
        for (int q = 0; q < 16; ++q) {
            h4 v = Z[SK(b3 + q)];
            re[q] = mk2((float)v.x, (float)v.y); im[q] = mk2((float)v.z, (float)v.w);
        }
        ip16<-1, false>(re, im);
#pragma unroll
        for (int m = 0; m < 16; ++m) {
            f2 r = re[m], i = im[m];
            re[m] = (r * r - i * i) * s;      // (re^2 - im^2) * s, both rows
            im[m] = (r * i) * (2.0f * s);     // 2*s*re*im, both rows
        }
        ip16<1, true>(re, im);
        __builtin_amdgcn_wave_barrier();
#pragma unroll
        for (int q = 0; q < 16; ++q) Z[SK(b3 + q)] = packh(re[q], im[q]);
        __builtin_amdgcn_wave_barrier();
    }

    // ---- inv stage 2 (stride 16): conj twiddle from registers, inverse dft ----
#pragma unroll
    for (int q = 0; q < 16; ++q) {
        h4 v = Z[SK(base + 16 * q)];
        re[q] = mk2((float)v.x, (float)v.y); im[q] = mk2((float)v.z, (float)v.w);
    }
#pragma unroll
    for (int q = 1; q < 16; ++q) TWC(q, wB2[q - 1]);
    ip16<1, false>(re, im);
    __builtin_amdgcn_wave_barrier();
#pragma unroll
    for (int m = 0; m < 16; ++m) Z[SK(base + 16 * PM(m))] = packh(re[m], im[m]);
    // prefetch inv3's twA set; latency hides under the barrier + inv3 ds_reads.
    // born after wB2 dies -> no twiddle-register overlap (r22 had 60 live here)
    cplx wA2[15];
#pragma unroll
    for (int q = 1; q < 16; ++q) wA2[q - 1] = twA[q * 256 + t];
    __syncthreads();   // next stage is stride-256: cross-wave

    // ---- inv stage 3 (stride 256), im-only final layer + coalesced store ----
#pragma unroll
    for (int q = 0; q < 16; ++q) {
        h4 v = Z[SK(t + 256 * q)];
        re[q] = mk2((float)v.x, (float)v.y); im[q] = mk2((float)v.z, (float)v.w);
    }
#pragma unroll
    for (int q = 1; q < 16; ++q) TWC(q, wA2[q - 1]);
    ip16<1, false, true>(re, im);   // IMONLY: final layer computes im outputs only
#pragma unroll
    for (int m = 0; m < 16; ++m) {
        int idx = t + 256 * PM(m);
        o0[idx] = im[m].x;
        o1[idx] = im[m].y;
    }
#undef TWF
#undef TWC
}

extern "C" void kernel_launch(void* const* d_in, const int* in_sizes, int n_in,
                              void* d_out, int out_size, void* d_ws, size_t ws_size,
                              hipStream_t stream) {
    const float* a = (const float*)d_in[0];
    const float* b = (const float*)d_in[1];
    float* out = (float*)d_out;
    cplx* twA = (cplx*)d_ws;              // 4096 cplx
    cplx* twB = twA + 4096;               // 256 cplx  (total 34 KB)
    const int B = in_sizes[0] / FFT_N;    // 8192 rows

    twiddle_init<<<17, NT, 0, stream>>>(twA, twB);        // 4352 entries
    circconv4096_kernel<<<B / 2, NT, 0, stream>>>(a, b, out, twA, twB);
}

// Round 24
// 103.498 us; speedup vs baseline: 1.0447x; 1.0447x over previous
//
#include <hip/hip_runtime.h>

#define FFT_N 4096
#define NT    256
// additive skew in 8-byte units: +1 per 16 (r19-verified: conflicts ~0.5e6)
#define SK(i) ((i) + ((i) >> 4))
// base-4 digit-reverse involution for 16: P(m) = ((m&3)<<2)|(m>>2)
#define PM(m) ((((m) & 3) << 2) | ((m) >> 2))

typedef float  f2  __attribute__((ext_vector_type(2)));  // lane = row: (row0, row1)
typedef __fp16 h2v __attribute__((ext_vector_type(2)));
typedef __fp16 h4  __attribute__((ext_vector_type(4)));  // LDS: re0, re1, im0, im1

__device__ __forceinline__ f2 mk2(float a, float b) { f2 v; v.x = a; v.y = b; return v; }
__device__ __forceinline__ h4 packh(f2 re, f2 im) {
    h2v r = __builtin_amdgcn_cvt_pkrtz(re.x, re.y);
    h2v i = __builtin_amdgcn_cvt_pkrtz(im.x, im.y);
    h4 v; v.x = r.x; v.y = r.y; v.z = i.x; v.w = i.y;
    return v;
}

// In-place 16-point DFT, SoA over rows (verified r18/r19/r22).
// IMONLY (SGN=+1, PERMIN=false only): final layer computes im outputs only
// (signs verified r23, absmax unchanged).
template <int SGN, bool PERMIN, bool IMONLY = false>
__device__ __forceinline__ void ip16(f2* re, f2* im) {
    const float C1 = 0.92387953251128675613f;   // cos(pi/8)
    const float S1 = 0.38268343236508977173f;   // sin(pi/8)
    const float R2 = 0.70710678118654752440f;   // sqrt(2)/2
#define BF4(i0, i1, i2, i3) do { \
        f2 t0r = re[i0] + re[i2], t0i = im[i0] + im[i2]; \
        f2 t1r = re[i0] - re[i2], t1i = im[i0] - im[i2]; \
        f2 t2r = re[i1] + re[i3], t2i = im[i1] + im[i3]; \
        f2 t3r = re[i1] - re[i3], t3i = im[i1] - im[i3]; \
        re[i0] = t0r + t2r; im[i0] = t0i + t2i; \
        re[i2] = t0r - t2r; im[i2] = t0i - t2i; \
        if (SGN < 0) { re[i1] = t1r + t3i; im[i1] = t1i - t3r; \
                       re[i3] = t1r - t3i; im[i3] = t1i + t3r; } \
        else         { re[i1] = t1r - t3i; im[i1] = t1i + t3r; \
                       re[i3] = t1r + t3i; im[i3] = t1i - t3r; } \
    } while (0)
#define BF4IM(i0, i1, i2, i3) do { \
        f2 t0i = im[i0] + im[i2], t1i = im[i0] - im[i2]; \
        f2 t2i = im[i1] + im[i3], t3r = re[i1] - re[i3]; \
        im[i0] = t0i + t2i; im[i2] = t0i - t2i; \
        im[i1] = t1i + t3r; im[i3] = t1i - t3r; \
    } while (0)
#define TWM(m, cr, ci) do { \
        f2 rr_ = re[m], ii_ = im[m]; \
        if (SGN < 0) { re[m] = rr_ * (cr) + ii_ * (ci); im[m] = ii_ * (cr) - rr_ * (ci); } \
        else         { re[m] = rr_ * (cr) - ii_ * (ci); im[m] = ii_ * (cr) + rr_ * (ci); } \
    } while (0)
    if (!PERMIN) { BF4(0, 4, 8, 12); BF4(1, 5, 9, 13); BF4(2, 6, 10, 14); BF4(3, 7, 11, 15); }
    else         { BF4(0, 1, 2, 3);  BF4(4, 5, 6, 7);  BF4(8, 9, 10, 11); BF4(12, 13, 14, 15); }
    TWM(5,  C1, S1);    // w1
    TWM(6,  R2, R2);    // w2
    TWM(7,  S1, C1);    // w3
    TWM(9,  R2, R2);    // w2
    {   // x[10] *= S*i
        f2 rr_ = re[10], ii_ = im[10];
        if (SGN < 0) { re[10] = ii_; im[10] = mk2(0.f, 0.f) - rr_; }
        else         { re[10] = mk2(0.f, 0.f) - ii_; im[10] = rr_; }
    }
    TWM(11, -R2, R2);   // w6
    TWM(13, S1, C1);    // w3
    TWM(14, -R2, R2);   // w6
    TWM(15, -C1, -S1);  // w9
    if (!PERMIN) {
        if (IMONLY) { BF4IM(0, 1, 2, 3); BF4IM(4, 5, 6, 7); BF4IM(8, 9, 10, 11); BF4IM(12, 13, 14, 15); }
        else        { BF4(0, 1, 2, 3);   BF4(4, 5, 6, 7);   BF4(8, 9, 10, 11);   BF4(12, 13, 14, 15); }
    } else { BF4(0, 4, 8, 12); BF4(1, 5, 9, 13); BF4(2, 6, 10, 14); BF4(3, 7, 11, 15); }
#undef BF4
#undef BF4IM
#undef TWM
}

typedef float cplx __attribute__((ext_vector_type(2)));
// d_ws: twA[4096] = W4096^(t*r) at [r*256+t]; twB[256] = W256^(j*r) at [r*16+j]
__global__ void twiddle_init(cplx* __restrict__ twA, cplx* __restrict__ twB) {
    int m = blockIdx.x * NT + threadIdx.x;   // 0..4351
    if (m >= 4352) return;
    float s, c;
    if (m < 4096) {
        int r = m >> 8, t = m & 255;
        sincosf(-6.28318530717958647692f * (float)(t * r) / 4096.0f, &s, &c);
        cplx v; v.x = c; v.y = s; twA[m] = v;
    } else {
        int k = m - 4096;                    // k = r*16 + j
        int r = k >> 4, j = k & 15;
        sincosf(-6.28318530717958647692f * (float)(j * r) / 256.0f, &s, &c);
        cplx v; v.x = c; v.y = s; twB[k] = v;
    }
}

__global__ __launch_bounds__(NT) void circconv4096_kernel(
    const float* __restrict__ A, const float* __restrict__ Bv,
    float* __restrict__ O,
    const cplx* __restrict__ twA, const cplx* __restrict__ twB)
{
    // two rows per block, row-packed 4xf16 per element (b64): 34.8 KB -> 4 blocks/CU
    __shared__ h4 Z[SK(4095) + 1];
    const int t = threadIdx.x;
    const size_t r0 = (size_t)blockIdx.x * 2;
    const float* a0 = A + r0 * FFT_N;
    const float* b0 = Bv + r0 * FFT_N;
    const float* a1 = a0 + FFT_N;
    const float* b1 = b0 + FFT_N;
    float* o0 = O + r0 * FFT_N;
    float* o1 = o0 + FFT_N;

    f2 re[16], im[16];

#define TWF(m, w) do { f2 rr_ = re[m], ii_ = im[m]; float wr_ = (w).x, wi_ = (w).y; \
        re[m] = rr_ * wr_ - ii_ * wi_; im[m] = rr_ * wi_ + ii_ * wr_; } while (0)
#define TWC(m, w) do { f2 rr_ = re[m], ii_ = im[m]; float wr_ = (w).x, wi_ = (w).y; \
        re[m] = rr_ * wr_ + ii_ * wi_; im[m] = ii_ * wr_ - rr_ * wi_; } while (0)

    const int j = t & 15;
    const int base = ((t >> 4) << 8) + j;

    // ---- fwd stage 1 (stride 256): coalesced loads, both rows ----
#pragma unroll
    for (int q = 0; q < 16; ++q) {
        int g = t + 256 * q;
        re[q] = mk2(a0[g], a1[g]);
        im[q] = mk2(b0[g], b1[g]);   // z = a + i*b per row
    }
    // PREFETCH twB set before the barrier: used by fwd2 (PM order) AND inv2 (natural)
    cplx wB[15];
#pragma unroll
    for (int q = 1; q < 16; ++q) wB[q - 1] = twB[q * 16 + j];

    ip16<-1, false>(re, im);
#pragma unroll
    for (int m = 1; m < 16; ++m) { cplx w = twA[PM(m) * 256 + t]; TWF(m, w); }
#pragma unroll
    for (int m = 0; m < 16; ++m) Z[SK(t + 256 * PM(m))] = packh(re[m], im[m]);
    __syncthreads();

    // ---- fwd stage 2 (stride 16, wave-private): twiddles already in registers ----
#pragma unroll
    for (int q = 0; q < 16; ++q) {
        h4 v = Z[SK(base + 16 * q)];
        re[q] = mk2((float)v.x, (float)v.y); im[q] = mk2((float)v.z, (float)v.w);
    }
    ip16<-1, false>(re, im);
#pragma unroll
    for (int m = 1; m < 16; ++m) TWF(m, wB[PM(m) - 1]);
    __builtin_amdgcn_wave_barrier();
#pragma unroll
    for (int m = 0; m < 16; ++m) Z[SK(base + 16 * PM(m))] = packh(re[m], im[m]);
    __builtin_amdgcn_wave_barrier();

    // ---- fwd stage 3 (contig) + scaled square + inv stage 1 (contig) ----
    {
        const int b3 = t * 16;
        const float s = 1.0f / 8192.0f;   // fold /4096 (ifft) and /2 (imag trick)
#pragma unroll
        for (int q = 0; q < 16; ++q) {
            h4 v = Z[SK(b3 + q)];
            re[q] = mk2((float)v.x, (float)v.y); im[q] = mk2((float)v.z, (float)v.w);
        }
        ip16<-1, false>(re, im);
#pragma unroll
        for (int m = 0; m < 16; ++m) {
            f2 r = re[m], i = im[m];
            re[m] = (r * r - i * i) * s;      // (re^2 - im^2) * s, both rows
            im[m] = (r * i) * (2.0f * s);     // 2*s*re*im, both rows
        }
        ip16<1, true>(re, im);
        __builtin_amdgcn_wave_barrier();
#pragma unroll
        for (int q = 0; q < 16; ++q) Z[SK(b3 + q)] = packh(re[q], im[q]);
        __builtin_amdgcn_wave_barrier();
    }

    // ---- inv stage 2 (stride 16): conj twiddle from registers, inverse dft ----
#pragma unroll
    for (int q = 0; q < 16; ++q) {
        h4 v = Z[SK(base + 16 * q)];
        re[q] = mk2((float)v.x, (float)v.y); im[q] = mk2((float)v.z, (float)v.w);
    }
#pragma unroll
    for (int q = 1; q < 16; ++q) TWC(q, wB[q - 1]);
    // PREFETCH inv3's twA set now (wB dead): latency hides under ip16 + barrier
    cplx wA2[15];
#pragma unroll
    for (int q = 1; q < 16; ++q) wA2[q - 1] = twA[q * 256 + t];
    ip16<1, false>(re, im);
    __builtin_amdgcn_wave_barrier();
#pragma unroll
    for (int m = 0; m < 16; ++m) Z[SK(base + 16 * PM(m))] = packh(re[m], im[m]);
    __syncthreads();   // next stage is stride-256: cross-wave

    // ---- inv stage 3 (stride 256), im-only final layer + coalesced store ----
#pragma unroll
    for (int q = 0; q < 16; ++q) {
        h4 v = Z[SK(t + 256 * q)];
        re[q] = mk2((float)v.x, (float)v.y); im[q] = mk2((float)v.z, (float)v.w);
    }
#pragma unroll
    for (int q = 1; q < 16; ++q) TWC(q, wA2[q - 1]);
    ip16<1, false, true>(re, im);   // IMONLY: final layer computes im outputs only
#pragma unroll
    for (int m = 0; m < 16; ++m) {
        int idx = t + 256 * PM(m);
        o0[idx] = im[m].x;
        o1[idx] = im[m].y;
    }
#undef TWF
#undef TWC
}

extern "C" void kernel_launch(void* const* d_in, const int* in_sizes, int n_in,
                              void* d_out, int out_size, void* d_ws, size_t ws_size,
                              hipStream_t stream) {
    const float* a = (const float*)d_in[0];
    const float* b = (const float*)d_in[1];
    float* out = (float*)d_out;
    cplx* twA = (cplx*)d_ws;              // 4096 cplx
    cplx* twB = twA + 4096;               // 256 cplx  (total 34 KB)
    const int B = in_sizes[0] / FFT_N;    // 8192 rows

    twiddle_init<<<17, NT, 0, stream>>>(twA, twB);        // 4352 entries
    circconv4096_kernel<<<B / 2, NT, 0, stream>>>(a, b, out, twA, twB);
}

// Round 25
// 96.025 us; speedup vs baseline: 1.1260x; 1.0778x over previous
//
#include <hip/hip_runtime.h>

#define FFT_N 4096
#define NT    256
// additive skew in 8-byte units: +1 per 16 (r19-verified: conflicts ~0.5e6)
#define SK(i) ((i) + ((i) >> 4))
// base-4 digit-reverse involution for 16: P(m) = ((m&3)<<2)|(m>>2)
#define PM(m) ((((m) & 3) << 2) | ((m) >> 2))

typedef float  f2  __attribute__((ext_vector_type(2)));  // lane = row: (row0, row1) f32
typedef __fp16 h2v __attribute__((ext_vector_type(2)));  // lane = row: (row0, row1) f16
typedef __fp16 h4  __attribute__((ext_vector_type(4)));  // LDS: re0, re1, im0, im1

__device__ __forceinline__ f2 mk2(float a, float b) { f2 v; v.x = a; v.y = b; return v; }
__device__ __forceinline__ h4 packh(f2 re, f2 im) {
    h2v r = __builtin_amdgcn_cvt_pkrtz(re.x, re.y);
    h2v i = __builtin_amdgcn_cvt_pkrtz(im.x, im.y);
    h4 v; v.x = r.x; v.y = r.y; v.z = i.x; v.w = i.y;
    return v;
}
__device__ __forceinline__ h2v mkh(__fp16 a, __fp16 b) { h2v v; v.x = a; v.y = b; return v; }
__device__ __forceinline__ h4 cath(h2v r, h2v i) {      // free register concat
    h4 v; v.x = r.x; v.y = r.y; v.z = i.x; v.w = i.y;
    return v;
}

// f32 in-place 16-point DFT, SoA over rows (verified r18/r19/r22).
// IMONLY (SGN=+1, PERMIN=false): final layer computes im outputs only (verified r23/r24).
template <int SGN, bool PERMIN, bool IMONLY = false>
__device__ __forceinline__ void ip16(f2* re, f2* im) {
    const float C1 = 0.92387953251128675613f;   // cos(pi/8)
    const float S1 = 0.38268343236508977173f;   // sin(pi/8)
    const float R2 = 0.70710678118654752440f;   // sqrt(2)/2
#define BF4(i0, i1, i2, i3) do { \
        f2 t0r = re[i0] + re[i2], t0i = im[i0] + im[i2]; \
        f2 t1r = re[i0] - re[i2], t1i = im[i0] - im[i2]; \
        f2 t2r = re[i1] + re[i3], t2i = im[i1] + im[i3]; \
        f2 t3r = re[i1] - re[i3], t3i = im[i1] - im[i3]; \
        re[i0] = t0r + t2r; im[i0] = t0i + t2i; \
        re[i2] = t0r - t2r; im[i2] = t0i - t2i; \
        if (SGN < 0) { re[i1] = t1r + t3i; im[i1] = t1i - t3r; \
                       re[i3] = t1r - t3i; im[i3] = t1i + t3r; } \
        else         { re[i1] = t1r - t3i; im[i1] = t1i + t3r; \
                       re[i3] = t1r + t3i; im[i3] = t1i - t3r; } \
    } while (0)
#define BF4IM(i0, i1, i2, i3) do { \
        f2 t0i = im[i0] + im[i2], t1i = im[i0] - im[i2]; \
        f2 t2i = im[i1] + im[i3], t3r = re[i1] - re[i3]; \
        im[i0] = t0i + t2i; im[i2] = t0i - t2i; \
        im[i1] = t1i + t3r; im[i3] = t1i - t3r; \
    } while (0)
#define TWM(m, cr, ci) do { \
        f2 rr_ = re[m], ii_ = im[m]; \
        if (SGN < 0) { re[m] = rr_ * (cr) + ii_ * (ci); im[m] = ii_ * (cr) - rr_ * (ci); } \
        else         { re[m] = rr_ * (cr) - ii_ * (ci); im[m] = ii_ * (cr) + rr_ * (ci); } \
    } while (0)
    if (!PERMIN) { BF4(0, 4, 8, 12); BF4(1, 5, 9, 13); BF4(2, 6, 10, 14); BF4(3, 7, 11, 15); }
    else         { BF4(0, 1, 2, 3);  BF4(4, 5, 6, 7);  BF4(8, 9, 10, 11); BF4(12, 13, 14, 15); }
    TWM(5,  C1, S1);    // w1
    TWM(6,  R2, R2);    // w2
    TWM(7,  S1, C1);    // w3
    TWM(9,  R2, R2);    // w2
    {   // x[10] *= S*i
        f2 rr_ = re[10], ii_ = im[10];
        if (SGN < 0) { re[10] = ii_; im[10] = mk2(0.f, 0.f) - rr_; }
        else         { re[10] = mk2(0.f, 0.f) - ii_; im[10] = rr_; }
    }
    TWM(11, -R2, R2);   // w6
    TWM(13, S1, C1);    // w3
    TWM(14, -R2, R2);   // w6
    TWM(15, -C1, -S1);  // w9
    if (!PERMIN) {
        if (IMONLY) { BF4IM(0, 1, 2, 3); BF4IM(4, 5, 6, 7); BF4IM(8, 9, 10, 11); BF4IM(12, 13, 14, 15); }
        else        { BF4(0, 1, 2, 3);   BF4(4, 5, 6, 7);   BF4(8, 9, 10, 11);   BF4(12, 13, 14, 15); }
    } else { BF4(0, 4, 8, 12); BF4(1, 5, 9, 13); BF4(2, 6, 10, 14); BF4(3, 7, 11, 15); }
#undef BF4
#undef BF4IM
#undef TWM
}

// f16 in-place 16-point DFT (PERMIN=false path only), packed v_pk_*_f16 over rows.
// Mirrors the verified ip16 structure sign-for-sign.
template <int SGN>
__device__ __forceinline__ void ip16h(h2v* re, h2v* im) {
    const __fp16 C1 = (__fp16)0.92387953f;
    const __fp16 S1 = (__fp16)0.38268343f;
    const __fp16 R2 = (__fp16)0.70710678f;
    const __fp16 nC1 = (__fp16)-0.92387953f;
    const __fp16 nS1 = (__fp16)-0.38268343f;
    const __fp16 nR2 = (__fp16)-0.70710678f;
#define BF4H(i0, i1, i2, i3) do { \
        h2v t0r = re[i0] + re[i2], t0i = im[i0] + im[i2]; \
        h2v t1r = re[i0] - re[i2], t1i = im[i0] - im[i2]; \
        h2v t2r = re[i1] + re[i3], t2i = im[i1] + im[i3]; \
        h2v t3r = re[i1] - re[i3], t3i = im[i1] - im[i3]; \
        re[i0] = t0r + t2r; im[i0] = t0i + t2i; \
        re[i2] = t0r - t2r; im[i2] = t0i - t2i; \
        if (SGN < 0) { re[i1] = t1r + t3i; im[i1] = t1i - t3r; \
                       re[i3] = t1r - t3i; im[i3] = t1i + t3r; } \
        else         { re[i1] = t1r - t3i; im[i1] = t1i + t3r; \
                       re[i3] = t1r + t3i; im[i3] = t1i - t3r; } \
    } while (0)
#define TWMH(m, cr, ci) do { \
        h2v rr_ = re[m], ii_ = im[m]; \
        if (SGN < 0) { re[m] = rr_ * (cr) + ii_ * (ci); im[m] = ii_ * (cr) - rr_ * (ci); } \
        else         { re[m] = rr_ * (cr) - ii_ * (ci); im[m] = ii_ * (cr) + rr_ * (ci); } \
    } while (0)
    BF4H(0, 4, 8, 12); BF4H(1, 5, 9, 13); BF4H(2, 6, 10, 14); BF4H(3, 7, 11, 15);
    TWMH(5,  C1, S1);    // w1
    TWMH(6,  R2, R2);    // w2
    TWMH(7,  S1, C1);    // w3
    TWMH(9,  R2, R2);    // w2
    {   // x[10] *= S*i
        h2v rr_ = re[10], ii_ = im[10];
        if (SGN < 0) { re[10] = ii_; im[10] = -rr_; }
        else         { re[10] = -ii_; im[10] = rr_; }
    }
    TWMH(11, nR2, R2);   // w6
    TWMH(13, S1, C1);    // w3
    TWMH(14, nR2, R2);   // w6
    TWMH(15, nC1, nS1);  // w9
    BF4H(0, 1, 2, 3);  BF4H(4, 5, 6, 7);  BF4H(8, 9, 10, 11); BF4H(12, 13, 14, 15);
#undef BF4H
#undef TWMH
}

typedef float cplx __attribute__((ext_vector_type(2)));
// d_ws: twA[4096] = W4096^(t*r) at [r*256+t]; twB[256] = W256^(j*r) at [r*16+j]
__global__ void twiddle_init(cplx* __restrict__ twA, cplx* __restrict__ twB) {
    int m = blockIdx.x * NT + threadIdx.x;   // 0..4351
    if (m >= 4352) return;
    float s, c;
    if (m < 4096) {
        int r = m >> 8, t = m & 255;
        sincosf(-6.28318530717958647692f * (float)(t * r) / 4096.0f, &s, &c);
        cplx v; v.x = c; v.y = s; twA[m] = v;
    } else {
        int k = m - 4096;                    // k = r*16 + j
        int r = k >> 4, j = k & 15;
        sincosf(-6.28318530717958647692f * (float)(j * r) / 256.0f, &s, &c);
        cplx v; v.x = c; v.y = s; twB[k] = v;
    }
}

__global__ __launch_bounds__(NT) void circconv4096_kernel(
    const float* __restrict__ A, const float* __restrict__ Bv,
    float* __restrict__ O,
    const cplx* __restrict__ twA, const cplx* __restrict__ twB)
{
    // two rows per block, row-packed 4xf16 per element (b64): 34.8 KB -> 4 blocks/CU
    __shared__ h4 Z[SK(4095) + 1];
    const int t = threadIdx.x;
    const size_t r0 = (size_t)blockIdx.x * 2;
    const float* a0 = A + r0 * FFT_N;
    const float* b0 = Bv + r0 * FFT_N;
    const float* a1 = a0 + FFT_N;
    const float* b1 = b0 + FFT_N;
    float* o0 = O + r0 * FFT_N;
    float* o1 = o0 + FFT_N;

    f2 re[16], im[16];

#define TWF(m, w) do { f2 rr_ = re[m], ii_ = im[m]; float wr_ = (w).x, wi_ = (w).y; \
        re[m] = rr_ * wr_ - ii_ * wi_; im[m] = rr_ * wi_ + ii_ * wr_; } while (0)
#define TWC(m, w) do { f2 rr_ = re[m], ii_ = im[m]; float wr_ = (w).x, wi_ = (w).y; \
        re[m] = rr_ * wr_ + ii_ * wi_; im[m] = ii_ * wr_ - rr_ * wi_; } while (0)
// f16 stage twiddles from broadcast h2v registers
#define TWFH(m, wr, wi) do { h2v rr_ = hre[m], ii_ = him[m]; \
        hre[m] = rr_ * (wr) - ii_ * (wi); him[m] = rr_ * (wi) + ii_ * (wr); } while (0)
#define TWCH(m, wr, wi) do { h2v rr_ = hre[m], ii_ = him[m]; \
        hre[m] = rr_ * (wr) + ii_ * (wi); him[m] = ii_ * (wr) - rr_ * (wi); } while (0)

    const int j = t & 15;
    const int base = ((t >> 4) << 8) + j;

    // ---- fwd stage 1 (stride 256): coalesced loads, both rows, f32 math ----
#pragma unroll
    for (int q = 0; q < 16; ++q) {
        int g = t + 256 * q;
        re[q] = mk2(a0[g], a1[g]);
        im[q] = mk2(b0[g], b1[g]);   // z = a + i*b per row
    }
    // PREFETCH twB set before the barrier, convert once to f16 broadcast pairs;
    // reused by fwd2 (PM order) AND inv2 (natural order)
    h2v wBr[15], wBi[15];
    {
#pragma unroll
        for (int q = 1; q < 16; ++q) {
            cplx w = twB[q * 16 + j];
            wBr[q - 1] = mkh((__fp16)w.x, (__fp16)w.x);
            wBi[q - 1] = mkh((__fp16)w.y, (__fp16)w.y);
        }
    }

    ip16<-1, false>(re, im);
#pragma unroll
    for (int m = 1; m < 16; ++m) { cplx w = twA[PM(m) * 256 + t]; TWF(m, w); }
#pragma unroll
    for (int m = 0; m < 16; ++m) Z[SK(t + 256 * PM(m))] = packh(re[m], im[m]);
    __syncthreads();

    // ---- fwd stage 2 (stride 16, wave-private): FULL f16 path, zero conversions ----
    {
        h2v hre[16], him[16];
#pragma unroll
        for (int q = 0; q < 16; ++q) {
            h4 v = Z[SK(base + 16 * q)];
            hre[q] = mkh(v.x, v.y); him[q] = mkh(v.z, v.w);   // register-half extract
        }
        ip16h<-1>(hre, him);
#pragma unroll
        for (int m = 1; m < 16; ++m) TWFH(m, wBr[PM(m) - 1], wBi[PM(m) - 1]);
        __builtin_amdgcn_wave_barrier();
#pragma unroll
        for (int m = 0; m < 16; ++m) Z[SK(base + 16 * PM(m))] = cath(hre[m], him[m]);
        __builtin_amdgcn_wave_barrier();
    }

    // ---- fwd stage 3 (contig) + scaled square + inv stage 1 (contig), f32 ----
    {
        const int b3 = t * 16;
        const float s = 1.0f / 8192.0f;   // fold /4096 (ifft) and /2 (imag trick)
#pragma unroll
        for (int q = 0; q < 16; ++q) {
            h4 v = Z[SK(b3 + q)];
            re[q] = mk2((float)v.x, (float)v.y); im[q] = mk2((float)v.z, (float)v.w);
        }
        ip16<-1, false>(re, im);
#pragma unroll
        for (int m = 0; m < 16; ++m) {
            f2 r = re[m], i = im[m];
            re[m] = (r * r - i * i) * s;      // (re^2 - im^2) * s, both rows
            im[m] = (r * i) * (2.0f * s);     // 2*s*re*im, both rows
        }
        ip16<1, true>(re, im);
        __builtin_amdgcn_wave_barrier();
#pragma unroll
        for (int q = 0; q < 16; ++q) Z[SK(b3 + q)] = packh(re[q], im[q]);
        __builtin_amdgcn_wave_barrier();
    }

    // ---- inv stage 2 (stride 16, wave-private): FULL f16 path ----
    cplx wA2[15];
    {
        h2v hre[16], him[16];
#pragma unroll
        for (int q = 0; q < 16; ++q) {
            h4 v = Z[SK(base + 16 * q)];
            hre[q] = mkh(v.x, v.y); him[q] = mkh(v.z, v.w);
        }
#pragma unroll
        for (int q = 1; q < 16; ++q) TWCH(q, wBr[q - 1], wBi[q - 1]);
        // PREFETCH inv3's twA set now (wB use done): latency hides under ip16h + barrier
#pragma unroll
        for (int q = 1; q < 16; ++q) wA2[q - 1] = twA[q * 256 + t];
        ip16h<1>(hre, him);
        __builtin_amdgcn_wave_barrier();
#pragma unroll
        for (int m = 0; m < 16; ++m) Z[SK(base + 16 * PM(m))] = cath(hre[m], him[m]);
    }
    __syncthreads();   // next stage is stride-256: cross-wave

    // ---- inv stage 3 (stride 256), f32, im-only final layer + coalesced store ----
#pragma unroll
    for (int q = 0; q < 16; ++q) {
        h4 v = Z[SK(t + 256 * q)];
        re[q] = mk2((float)v.x, (float)v.y); im[q] = mk2((float)v.z, (float)v.w);
    }
#pragma unroll
    for (int q = 1; q < 16; ++q) TWC(q, wA2[q - 1]);
    ip16<1, false, true>(re, im);   // IMONLY: final layer computes im outputs only
#pragma unroll
    for (int m = 0; m < 16; ++m) {
        int idx = t + 256 * PM(m);
        o0[idx] = im[m].x;
        o1[idx] = im[m].y;
    }
#undef TWF
#undef TWC
#undef TWFH
#undef TWCH
}

extern "C" void kernel_launch(void* const* d_in, const int* in_sizes, int n_in,
                              void* d_out, int out_size, void* d_ws, size_t ws_size,
                              hipStream_t stream) {
    const float* a = (const float*)d_in[0];
    const float* b = (const float*)d_in[1];
    float* out = (float*)d_out;
    cplx* twA = (cplx*)d_ws;              // 4096 cplx
    cplx* twB = twA + 4096;               // 256 cplx  (total 34 KB)
    const int B = in_sizes[0] / FFT_N;    // 8192 rows

    twiddle_init<<<17, NT, 0, stream>>>(twA, twB);        // 4352 entries
    circconv4096_kernel<<<B / 2, NT, 0, stream>>>(a, b, out, twA, twB);
}